// Round 5
// baseline (13341.270 us; speedup 1.0000x reference)
//
#include <hip/hip_runtime.h>
#include <math.h>

#define T_LEN 1024
#define B_SZ  256
#define I_SZ  128
#define H_SZ  64
#define G_SZ  256   // 4*H
#define TT    16    // timesteps per chunk (weight reuse factor)
#define NCHUNK (T_LEN / TT)

typedef float f32x8 __attribute__((ext_vector_type(8)));

__device__ __forceinline__ float fast_sigmoid(float x) {
    float e = __expf(-x);
    return __builtin_amdgcn_rcpf(1.0f + e);
}
__device__ __forceinline__ float fast_tanh(float x) {
    float e = __expf(-2.0f * fabsf(x));
    float r = (1.0f - e) * __builtin_amdgcn_rcpf(1.0f + e);
    return copysignf(r, x);
}

#define LD8(V, P)                                                           \
    {   float4 t0_ = *reinterpret_cast<const float4*>(P);                   \
        float4 t1_ = *reinterpret_cast<const float4*>((P) + 4);             \
        V = (f32x8){t0_.x, t0_.y, t0_.z, t0_.w, t1_.x, t1_.y, t1_.z, t1_.w}; }

#define LD8PIN(V, P)  { LD8(V, P) asm volatile("" : "+v"(V)); }

// ---------------------------------------------------------------------------
// Time-tiled forward LSTM scan. One block per batch element, 1024 threads.
// Thread (j = tid>>2, q = tid&3) owns a quarter of gate row j.
// Per chunk: stage x[16 steps] in LDS; stream W_ih tiles from L2 applying
// each tile to all 16 steps (xg[16] partial gates in regs, 16x weight reuse);
// then 16 fast recurrence steps using register-resident W_hh.
// x LDS layout: word (k&31) + 40*(k>>5) — the 4 q-groups hit disjoint banks.
// ---------------------------------------------------------------------------
__global__ __launch_bounds__(1024, 4) void lstm_fwd_scan(
    const float* __restrict__ x,      // [T,B,I]
    const float* __restrict__ W_ih,   // [256,128]
    const float* __restrict__ W_hh,   // [256,64]
    const float* __restrict__ bias,   // [256]
    float* __restrict__ h_out)        // [B,64]
{
    const int b   = blockIdx.x;
    const int tid = threadIdx.x;
    const int j   = tid >> 2;        // gate row 0..255
    const int q   = tid & 3;         // k-quarter 0..3

    __shared__ __align__(16) float xs[2][TT][160];  // swizzled x chunks (20KB)
    __shared__ __align__(16) float hs[H_SZ];
    __shared__ float gs[G_SZ];

    // W_hh quarter -> pinned registers (16 floats: no pressure)
    const float* ur = W_hh + j * H_SZ + q * 16;
    f32x8 u0, u1;
    LD8PIN(u0, ur) LD8PIN(u1, ur + 8)
    const float bj = (q == 0) ? bias[j] : 0.0f;
    const float* wrow = W_ih + j * I_SZ + q * 32;   // streamed per chunk

    // stage chunk 0 (each thread: 2 of the 2048 floats)
    const int k  = tid & 127;
    const int t0 = tid >> 7;                        // 0..7
    const int widx = (k & 31) + 40 * (k >> 5);
    {
        size_t base = ((size_t)t0 * B_SZ + b) * I_SZ + k;
        xs[0][t0][widx]     = x[base];
        xs[0][t0 + 8][widx] = x[base + (size_t)8 * B_SZ * I_SZ];
    }
    float c = 0.0f;
    if (tid < H_SZ) hs[tid] = 0.0f;
    __syncthreads();

    const int gate = tid >> 8;                      // wave-uniform: i,f,g,o

    for (int chunk = 0; chunk < NCHUNK; ++chunk) {
        const int cur = chunk & 1;

        // issue next-chunk global loads early (land during x-phase FMAs)
        const bool pf = (chunk + 1 < NCHUNK);
        float p0 = 0.0f, p1 = 0.0f;
        if (pf) {
            size_t base = ((size_t)((chunk + 1) * TT + t0) * B_SZ + b) * I_SZ + k;
            p0 = x[base];
            p1 = x[base + (size_t)8 * B_SZ * I_SZ];
        }

        // ---- x-phase: xg[t] = bj + dot(x_t[32q..32q+32), W_ih quarter)
        float xg[TT];
#pragma unroll
        for (int t = 0; t < TT; ++t) xg[t] = bj;
#pragma unroll
        for (int kk = 0; kk < 4; ++kk) {
            f32x8 w;
            LD8(w, wrow + 8 * kk)                   // L2-hot, reused 16x
#pragma unroll
            for (int t = 0; t < TT; ++t) {
                const float4* xp4 =
                    reinterpret_cast<const float4*>(&xs[cur][t][40 * q + 8 * kk]);
                const float4 xa = xp4[0], xb = xp4[1];
                float s = xg[t];
                s = fmaf(xa.x, w[0], s); s = fmaf(xa.y, w[1], s);
                s = fmaf(xa.z, w[2], s); s = fmaf(xa.w, w[3], s);
                s = fmaf(xb.x, w[4], s); s = fmaf(xb.y, w[5], s);
                s = fmaf(xb.z, w[6], s); s = fmaf(xb.w, w[7], s);
                xg[t] = s;
            }
        }

        // park prefetched x in the other buffer (chunk-boundary barriers fence)
        if (pf) {
            xs[cur ^ 1][t0][widx]     = p0;
            xs[cur ^ 1][t0 + 8][widx] = p1;
        }

        // ---- h-phase: 16 sequential recurrence steps
#pragma unroll
        for (int t = 0; t < TT; ++t) {
            float a0 = xg[t], a1 = 0.0f, a2 = 0.0f, a3 = 0.0f;
            const float4* hp = reinterpret_cast<const float4*>(&hs[16 * q]);
            const float4 h0 = hp[0], h1 = hp[1], h2 = hp[2], h3 = hp[3];
            a0 = fmaf(h0.x, u0[0], a0); a1 = fmaf(h0.y, u0[1], a1);
            a2 = fmaf(h0.z, u0[2], a2); a3 = fmaf(h0.w, u0[3], a3);
            a0 = fmaf(h1.x, u0[4], a0); a1 = fmaf(h1.y, u0[5], a1);
            a2 = fmaf(h1.z, u0[6], a2); a3 = fmaf(h1.w, u0[7], a3);
            a0 = fmaf(h2.x, u1[0], a0); a1 = fmaf(h2.y, u1[1], a1);
            a2 = fmaf(h2.z, u1[2], a2); a3 = fmaf(h2.w, u1[3], a3);
            a0 = fmaf(h3.x, u1[4], a0); a1 = fmaf(h3.y, u1[5], a1);
            a2 = fmaf(h3.z, u1[6], a2); a3 = fmaf(h3.w, u1[7], a3);

            float acc = (a0 + a1) + (a2 + a3);
            acc += __shfl_xor(acc, 1, 64);          // quad butterfly reduce
            acc += __shfl_xor(acc, 2, 64);

            const float a = (gate == 2) ? fast_tanh(acc) : fast_sigmoid(acc);
            if (q == 0) gs[j] = a;
            __syncthreads();                        // gs ready

            if (tid < H_SZ) {                       // cell update (wave 0)
                const float ig = gs[tid];
                const float fg = gs[H_SZ + tid];
                const float gg = gs[2 * H_SZ + tid];
                const float og = gs[3 * H_SZ + tid];
                c = fg * c + ig * gg;
                hs[tid] = og * fast_tanh(c);
            }
            __syncthreads();                        // hs ready
        }
    }

    if (tid < H_SZ) h_out[b * H_SZ + tid] = hs[tid];
}

// ---------------------------------------------------------------------------
// Reverse single cell (zero init state; W_hh_r drops out) + MLP head.
// ---------------------------------------------------------------------------
__global__ __launch_bounds__(256, 1) void lstm_tail(
    const float* __restrict__ x_last,  // [B,I]
    const float* __restrict__ W_ih_r,  // [256,128]
    const float* __restrict__ b_r,     // [256]
    const float* __restrict__ h_fwd,   // [B,64]
    const float* __restrict__ fc1_w,   // [64,128]
    const float* __restrict__ fc1_b,   // [64]
    const float* __restrict__ fc2_w,   // [32,64]
    const float* __restrict__ fc2_b,   // [32]
    const float* __restrict__ fc3_w,   // [10,32]
    const float* __restrict__ fc3_b,   // [10]
    float* __restrict__ out)           // [B,10]
{
    const int b = blockIdx.x;
    const int j = threadIdx.x;

    __shared__ float xs[I_SZ];
    __shared__ float gs[G_SZ];
    __shared__ float hc[2 * H_SZ];
    __shared__ float h1[64];
    __shared__ float h2[32];

    if (j < I_SZ) xs[j] = x_last[(size_t)b * I_SZ + j];
    if (j < H_SZ) hc[j] = h_fwd[b * H_SZ + j];
    __syncthreads();

    float a0 = b_r[j], a1 = 0.0f, a2 = 0.0f, a3 = 0.0f;
    const float* wrow = W_ih_r + j * I_SZ;
#pragma unroll
    for (int kk = 0; kk < I_SZ; kk += 4) {
        float4 wv = *reinterpret_cast<const float4*>(wrow + kk);
        a0 = fmaf(xs[kk + 0], wv.x, a0);
        a1 = fmaf(xs[kk + 1], wv.y, a1);
        a2 = fmaf(xs[kk + 2], wv.z, a2);
        a3 = fmaf(xs[kk + 3], wv.w, a3);
    }
    const float acc = (a0 + a1) + (a2 + a3);
    const int gate = j >> 6;
    gs[j] = (gate == 2) ? tanhf(acc) : 1.0f / (1.0f + expf(-acc));
    __syncthreads();

    if (j < H_SZ) {
        const float cc = gs[j] * gs[2 * H_SZ + j];     // i*g (c0 = 0)
        hc[H_SZ + j] = gs[3 * H_SZ + j] * tanhf(cc);
    }
    __syncthreads();

    if (j < 64) {
        float s0 = fc1_b[j], s1 = 0.0f, s2 = 0.0f, s3 = 0.0f;
        const float* w = fc1_w + j * 128;
#pragma unroll
        for (int kk = 0; kk < 128; kk += 4) {
            float4 wv = *reinterpret_cast<const float4*>(w + kk);
            s0 = fmaf(hc[kk + 0], wv.x, s0);
            s1 = fmaf(hc[kk + 1], wv.y, s1);
            s2 = fmaf(hc[kk + 2], wv.z, s2);
            s3 = fmaf(hc[kk + 3], wv.w, s3);
        }
        h1[j] = fmaxf((s0 + s1) + (s2 + s3), 0.0f);
    }
    __syncthreads();

    if (j < 32) {
        float s0 = fc2_b[j], s1 = 0.0f, s2 = 0.0f, s3 = 0.0f;
        const float* w = fc2_w + j * 64;
#pragma unroll
        for (int kk = 0; kk < 64; kk += 4) {
            float4 wv = *reinterpret_cast<const float4*>(w + kk);
            s0 = fmaf(h1[kk + 0], wv.x, s0);
            s1 = fmaf(h1[kk + 1], wv.y, s1);
            s2 = fmaf(h1[kk + 2], wv.z, s2);
            s3 = fmaf(h1[kk + 3], wv.w, s3);
        }
        h2[j] = fmaxf((s0 + s1) + (s2 + s3), 0.0f);
    }
    __syncthreads();

    if (j < 10) {
        float s = fc3_b[j];
#pragma unroll
        for (int kk = 0; kk < 32; ++kk) s = fmaf(h2[kk], fc3_w[j * 32 + kk], s);
        out[b * 10 + j] = s;
    }
}

extern "C" void kernel_launch(void* const* d_in, const int* in_sizes, int n_in,
                              void* d_out, int out_size, void* d_ws, size_t ws_size,
                              hipStream_t stream) {
    const float* x      = (const float*)d_in[0];
    const float* W_ih_f = (const float*)d_in[1];
    const float* W_hh_f = (const float*)d_in[2];
    const float* b_f    = (const float*)d_in[3];
    const float* W_ih_r = (const float*)d_in[4];
    // d_in[5] = W_hh_r : unused (zero initial state in reverse single step)
    const float* b_r    = (const float*)d_in[6];
    const float* fc1_w  = (const float*)d_in[7];
    const float* fc1_b  = (const float*)d_in[8];
    const float* fc2_w  = (const float*)d_in[9];
    const float* fc2_b  = (const float*)d_in[10];
    const float* fc3_w  = (const float*)d_in[11];
    const float* fc3_b  = (const float*)d_in[12];

    float* out   = (float*)d_out;
    float* h_fwd = (float*)d_ws;                  // [B,64] scratch

    const float* x_last = x + (size_t)(T_LEN - 1) * B_SZ * I_SZ;

    hipLaunchKernelGGL(lstm_fwd_scan, dim3(B_SZ), dim3(1024), 0, stream,
                       x, W_ih_f, W_hh_f, b_f, h_fwd);
    hipLaunchKernelGGL(lstm_tail, dim3(B_SZ), dim3(256), 0, stream,
                       x_last, W_ih_r, b_r, h_fwd,
                       fc1_w, fc1_b, fc2_w, fc2_b, fc3_w, fc3_b, out);
}

// Round 6
// 1053.729 us; speedup vs baseline: 12.6610x; 12.6610x over previous
//
#include <hip/hip_runtime.h>
#include <math.h>

#define T_LEN 1024
#define B_SZ  256
#define I_SZ  128
#define H_SZ  64
#define G_SZ  256   // 4*H

typedef float f32x8 __attribute__((ext_vector_type(8)));

__device__ __forceinline__ float fast_sigmoid(float x) {
    float e = __expf(-x);
    return __builtin_amdgcn_rcpf(1.0f + e);
}
__device__ __forceinline__ float fast_tanh(float x) {
    float e = __expf(-2.0f * fabsf(x));
    float r = (1.0f - e) * __builtin_amdgcn_rcpf(1.0f + e);
    return copysignf(r, x);
}

#define LD8PIN(V, P)                                                        \
    {   float4 t0_ = *reinterpret_cast<const float4*>(P);                   \
        float4 t1_ = *reinterpret_cast<const float4*>((P) + 4);             \
        V = (f32x8){t0_.x, t0_.y, t0_.z, t0_.w, t1_.x, t1_.y, t1_.z, t1_.w};\
        asm volatile("" : "+v"(V)); }

// LDS column swizzle: insert 4-float pad every 32 columns (keeps float4
// alignment; spreads the 4 aliasing groups of a 128-col tile across banks)
__device__ __forceinline__ int swz(int c) { return c + 4 * (c >> 5); }

// ---------------------------------------------------------------------------
// XG GEMM: XG[m][n] = dot(x[m][:], W_ih[n][:]) + bias[n]
//   m = t_local*B + b (rows of chunk), n = gate 0..255, K = 128.
// 128x128 block tile, 256 threads, 8x8 register micro-tile, K staged in 4x32.
// ---------------------------------------------------------------------------
__global__ __launch_bounds__(256, 2) void xg_gemm(
    const float* __restrict__ xch,    // [Mc,128] chunk of x
    const float* __restrict__ W_ih,   // [256,128]
    const float* __restrict__ bias,   // [256]
    float* __restrict__ XG)           // [Mc,256]
{
    const int tid = threadIdx.x;
    const int tx  = tid & 15;         // n-dir 0..15
    const int ty  = tid >> 4;         // m-dir 0..15
    const int mt  = blockIdx.x;       // m-tile
    const int nt  = blockIdx.y;       // n-tile (0..1)

    __shared__ __align__(16) float as[32][140];
    __shared__ __align__(16) float bs[32][140];

    // bias for this thread's 8 columns
    const int n0 = nt * 128 + tx * 8;
    float4 bia = *reinterpret_cast<const float4*>(&bias[n0]);
    float4 bib = *reinterpret_cast<const float4*>(&bias[n0 + 4]);

    float acc[8][8];
#pragma unroll
    for (int r = 0; r < 8; ++r)
#pragma unroll
        for (int cc = 0; cc < 8; ++cc) acc[r][cc] = 0.0f;

    // staging coords: 4 rows (stride 32) x one float4 of k per thread
    const int srow = tid >> 3;            // 0..31
    const int skk  = (tid & 7) * 4;       // 0,4,..,28

    for (int ks = 0; ks < 4; ++ks) {
        const int k0 = ks * 32;
        __syncthreads();                  // protect prev-iter reads
#pragma unroll
        for (int i = 0; i < 4; ++i) {
            const int mr = srow + 32 * i;
            float4 xa = *reinterpret_cast<const float4*>(
                &xch[(size_t)(mt * 128 + mr) * I_SZ + k0 + skk]);
            as[skk + 0][swz(mr)] = xa.x; as[skk + 1][swz(mr)] = xa.y;
            as[skk + 2][swz(mr)] = xa.z; as[skk + 3][swz(mr)] = xa.w;
            float4 wa = *reinterpret_cast<const float4*>(
                &W_ih[(size_t)(nt * 128 + mr) * I_SZ + k0 + skk]);
            bs[skk + 0][swz(mr)] = wa.x; bs[skk + 1][swz(mr)] = wa.y;
            bs[skk + 2][swz(mr)] = wa.z; bs[skk + 3][swz(mr)] = wa.w;
        }
        __syncthreads();

#pragma unroll 8
        for (int kk = 0; kk < 32; ++kk) {
            const float4 a0 = *reinterpret_cast<const float4*>(&as[kk][swz(ty * 8)]);
            const float4 a1 = *reinterpret_cast<const float4*>(&as[kk][swz(ty * 8) + 4]);
            const float4 b0 = *reinterpret_cast<const float4*>(&bs[kk][swz(tx * 8)]);
            const float4 b1 = *reinterpret_cast<const float4*>(&bs[kk][swz(tx * 8) + 4]);
            const float av[8] = {a0.x, a0.y, a0.z, a0.w, a1.x, a1.y, a1.z, a1.w};
            const float bv[8] = {b0.x, b0.y, b0.z, b0.w, b1.x, b1.y, b1.z, b1.w};
#pragma unroll
            for (int r = 0; r < 8; ++r)
#pragma unroll
                for (int cc = 0; cc < 8; ++cc)
                    acc[r][cc] = fmaf(av[r], bv[cc], acc[r][cc]);
        }
    }

    // epilogue: add bias, write XG
#pragma unroll
    for (int r = 0; r < 8; ++r) {
        const size_t m = (size_t)(mt * 128 + ty * 8 + r);
        float4 o0 = {acc[r][0] + bia.x, acc[r][1] + bia.y,
                     acc[r][2] + bia.z, acc[r][3] + bia.w};
        float4 o1 = {acc[r][4] + bib.x, acc[r][5] + bib.y,
                     acc[r][6] + bib.z, acc[r][7] + bib.w};
        *reinterpret_cast<float4*>(&XG[m * G_SZ + n0])     = o0;
        *reinterpret_cast<float4*>(&XG[m * G_SZ + n0 + 4]) = o1;
    }
}

// ---------------------------------------------------------------------------
// Lean recurrence over one time chunk. One block per batch element, 1024
// threads; thread (j = tid>>2, q = tid&3) owns a quarter of gate row j with
// 16 register-resident W_hh floats. XG provides x@W+b precomputed.
// h/c state carried in ws across chunk launches.
// ---------------------------------------------------------------------------
__global__ __launch_bounds__(1024, 4) void lstm_rec(
    const float* __restrict__ XG,     // [TC,B,256]
    const float* __restrict__ W_hh,   // [256,64]
    float* __restrict__ h_state,      // [B,64]
    float* __restrict__ c_state,      // [B,64]
    int TC, int first)
{
    const int b   = blockIdx.x;
    const int tid = threadIdx.x;
    const int j   = tid >> 2;
    const int q   = tid & 3;

    __shared__ __align__(16) float hs[H_SZ];
    __shared__ float gs[G_SZ];

    const float* ur = W_hh + j * H_SZ + q * 16;
    f32x8 u0, u1;
    LD8PIN(u0, ur) LD8PIN(u1, ur + 8)

    float c = 0.0f;
    if (tid < H_SZ) {
        hs[tid] = first ? 0.0f : h_state[b * H_SZ + tid];
        c       = first ? 0.0f : c_state[b * H_SZ + tid];
    }
    __syncthreads();

    const float* xgp = XG + (size_t)b * G_SZ + j;
    const size_t tstride = (size_t)B_SZ * G_SZ;
    const int gate = tid >> 8;                    // wave-uniform
    const float qsel = (q == 0) ? 1.0f : 0.0f;

    float xg_cur = xgp[0];
    for (int t = 0; t < TC; ++t) {
        float xg_next = 0.0f;
        if (t + 1 < TC) xg_next = xgp[(size_t)(t + 1) * tstride];  // prefetch

        float a0 = xg_cur * qsel, a1 = 0.0f, a2 = 0.0f, a3 = 0.0f;
        const float4* hp = reinterpret_cast<const float4*>(&hs[16 * q]);
        const float4 h0 = hp[0], h1 = hp[1], h2 = hp[2], h3 = hp[3];
        a0 = fmaf(h0.x, u0[0], a0); a1 = fmaf(h0.y, u0[1], a1);
        a2 = fmaf(h0.z, u0[2], a2); a3 = fmaf(h0.w, u0[3], a3);
        a0 = fmaf(h1.x, u0[4], a0); a1 = fmaf(h1.y, u0[5], a1);
        a2 = fmaf(h1.z, u0[6], a2); a3 = fmaf(h1.w, u0[7], a3);
        a0 = fmaf(h2.x, u1[0], a0); a1 = fmaf(h2.y, u1[1], a1);
        a2 = fmaf(h2.z, u1[2], a2); a3 = fmaf(h2.w, u1[3], a3);
        a0 = fmaf(h3.x, u1[4], a0); a1 = fmaf(h3.y, u1[5], a1);
        a2 = fmaf(h3.z, u1[6], a2); a3 = fmaf(h3.w, u1[7], a3);

        float acc = (a0 + a1) + (a2 + a3);
        acc += __shfl_xor(acc, 1, 64);
        acc += __shfl_xor(acc, 2, 64);

        const float a = (gate == 2) ? fast_tanh(acc) : fast_sigmoid(acc);
        if (q == 0) gs[j] = a;
        __syncthreads();                          // gs ready

        if (tid < H_SZ) {
            const float ig = gs[tid];
            const float fg = gs[H_SZ + tid];
            const float gg = gs[2 * H_SZ + tid];
            const float og = gs[3 * H_SZ + tid];
            c = fg * c + ig * gg;
            hs[tid] = og * fast_tanh(c);
        }
        __syncthreads();                          // hs ready
        xg_cur = xg_next;
    }

    if (tid < H_SZ) {
        h_state[b * H_SZ + tid] = hs[tid];
        c_state[b * H_SZ + tid] = c;
    }
}

// ---------------------------------------------------------------------------
// Reverse single cell (zero init state; W_hh_r drops out) + MLP head.
// ---------------------------------------------------------------------------
__global__ __launch_bounds__(256, 1) void lstm_tail(
    const float* __restrict__ x_last,  // [B,I]
    const float* __restrict__ W_ih_r,  // [256,128]
    const float* __restrict__ b_r,     // [256]
    const float* __restrict__ h_fwd,   // [B,64]
    const float* __restrict__ fc1_w,   // [64,128]
    const float* __restrict__ fc1_b,   // [64]
    const float* __restrict__ fc2_w,   // [32,64]
    const float* __restrict__ fc2_b,   // [32]
    const float* __restrict__ fc3_w,   // [10,32]
    const float* __restrict__ fc3_b,   // [10]
    float* __restrict__ out)           // [B,10]
{
    const int b = blockIdx.x;
    const int j = threadIdx.x;

    __shared__ float xs[I_SZ];
    __shared__ float gs[G_SZ];
    __shared__ float hc[2 * H_SZ];
    __shared__ float h1[64];
    __shared__ float h2[32];

    if (j < I_SZ) xs[j] = x_last[(size_t)b * I_SZ + j];
    if (j < H_SZ) hc[j] = h_fwd[b * H_SZ + j];
    __syncthreads();

    float a0 = b_r[j], a1 = 0.0f, a2 = 0.0f, a3 = 0.0f;
    const float* wrow = W_ih_r + j * I_SZ;
#pragma unroll
    for (int kk = 0; kk < I_SZ; kk += 4) {
        float4 wv = *reinterpret_cast<const float4*>(wrow + kk);
        a0 = fmaf(xs[kk + 0], wv.x, a0);
        a1 = fmaf(xs[kk + 1], wv.y, a1);
        a2 = fmaf(xs[kk + 2], wv.z, a2);
        a3 = fmaf(xs[kk + 3], wv.w, a3);
    }
    const float acc = (a0 + a1) + (a2 + a3);
    const int gate = j >> 6;
    gs[j] = (gate == 2) ? tanhf(acc) : 1.0f / (1.0f + expf(-acc));
    __syncthreads();

    if (j < H_SZ) {
        const float cc = gs[j] * gs[2 * H_SZ + j];     // i*g (c0 = 0)
        hc[H_SZ + j] = gs[3 * H_SZ + j] * tanhf(cc);
    }
    __syncthreads();

    if (j < 64) {
        float s0 = fc1_b[j], s1 = 0.0f, s2 = 0.0f, s3 = 0.0f;
        const float* w = fc1_w + j * 128;
#pragma unroll
        for (int kk = 0; kk < 128; kk += 4) {
            float4 wv = *reinterpret_cast<const float4*>(w + kk);
            s0 = fmaf(hc[kk + 0], wv.x, s0);
            s1 = fmaf(hc[kk + 1], wv.y, s1);
            s2 = fmaf(hc[kk + 2], wv.z, s2);
            s3 = fmaf(hc[kk + 3], wv.w, s3);
        }
        h1[j] = fmaxf((s0 + s1) + (s2 + s3), 0.0f);
    }
    __syncthreads();

    if (j < 32) {
        float s0 = fc2_b[j], s1 = 0.0f, s2 = 0.0f, s3 = 0.0f;
        const float* w = fc2_w + j * 64;
#pragma unroll
        for (int kk = 0; kk < 64; kk += 4) {
            float4 wv = *reinterpret_cast<const float4*>(w + kk);
            s0 = fmaf(h1[kk + 0], wv.x, s0);
            s1 = fmaf(h1[kk + 1], wv.y, s1);
            s2 = fmaf(h1[kk + 2], wv.z, s2);
            s3 = fmaf(h1[kk + 3], wv.w, s3);
        }
        h2[j] = fmaxf((s0 + s1) + (s2 + s3), 0.0f);
    }
    __syncthreads();

    if (j < 10) {
        float s = fc3_b[j];
#pragma unroll
        for (int kk = 0; kk < 32; ++kk) s = fmaf(h2[kk], fc3_w[j * 32 + kk], s);
        out[b * 10 + j] = s;
    }
}

extern "C" void kernel_launch(void* const* d_in, const int* in_sizes, int n_in,
                              void* d_out, int out_size, void* d_ws, size_t ws_size,
                              hipStream_t stream) {
    const float* x      = (const float*)d_in[0];
    const float* W_ih_f = (const float*)d_in[1];
    const float* W_hh_f = (const float*)d_in[2];
    const float* b_f    = (const float*)d_in[3];
    const float* W_ih_r = (const float*)d_in[4];
    // d_in[5] = W_hh_r : unused (zero initial state in reverse single step)
    const float* b_r    = (const float*)d_in[6];
    const float* fc1_w  = (const float*)d_in[7];
    const float* fc1_b  = (const float*)d_in[8];
    const float* fc2_w  = (const float*)d_in[9];
    const float* fc2_b  = (const float*)d_in[10];
    const float* fc3_w  = (const float*)d_in[11];
    const float* fc3_b  = (const float*)d_in[12];
    float* out = (float*)d_out;

    // time-chunk size: largest TC whose XG buffer (+state) fits in ws
    int TC = 1024;
    while (TC > 8 &&
           (size_t)TC * B_SZ * G_SZ * 4 + 2 * B_SZ * H_SZ * 4 > ws_size)
        TC >>= 1;

    float* XG      = (float*)d_ws;
    float* h_state = (float*)((char*)d_ws + (size_t)TC * B_SZ * G_SZ * 4);
    float* c_state = h_state + B_SZ * H_SZ;

    const int NCH = T_LEN / TC;
    for (int ch = 0; ch < NCH; ++ch) {
        const float* xch = x + (size_t)ch * TC * B_SZ * I_SZ;
        hipLaunchKernelGGL(xg_gemm, dim3(TC * B_SZ / 128, 2), dim3(256), 0,
                           stream, xch, W_ih_f, b_f, XG);
        hipLaunchKernelGGL(lstm_rec, dim3(B_SZ), dim3(1024), 0, stream,
                           XG, W_hh_f, h_state, c_state, TC, ch == 0 ? 1 : 0);
    }

    const float* x_last = x + (size_t)(T_LEN - 1) * B_SZ * I_SZ;
    hipLaunchKernelGGL(lstm_tail, dim3(B_SZ), dim3(256), 0, stream,
                       x_last, W_ih_r, b_r, h_state,
                       fc1_w, fc1_b, fc2_w, fc2_b, fc3_w, fc3_b, out);
}

// Round 7
// 692.202 us; speedup vs baseline: 19.2737x; 1.5223x over previous
//
#include <hip/hip_runtime.h>
#include <math.h>

#define T_LEN 1024
#define B_SZ  256
#define I_SZ  128
#define H_SZ  64
#define G_SZ  256   // 4*H
#define SUB   32    // recurrence steps per LDS-staged XG sub-chunk
#define XROW  260   // padded LDS row stride for XG (+4 words / 256)

typedef float f32x8 __attribute__((ext_vector_type(8)));
typedef float f32x4 __attribute__((ext_vector_type(4)));

__device__ __forceinline__ float fast_sigmoid(float x) {
    float e = __expf(-x);
    return __builtin_amdgcn_rcpf(1.0f + e);
}
__device__ __forceinline__ float fast_tanh(float x) {
    float e = __expf(-2.0f * fabsf(x));
    float r = (1.0f - e) * __builtin_amdgcn_rcpf(1.0f + e);
    return copysignf(r, x);
}

#define LD8PIN(V, P)                                                        \
    {   float4 t0_ = *reinterpret_cast<const float4*>(P);                   \
        float4 t1_ = *reinterpret_cast<const float4*>((P) + 4);             \
        V = (f32x8){t0_.x, t0_.y, t0_.z, t0_.w, t1_.x, t1_.y, t1_.z, t1_.w};\
        asm volatile("" : "+v"(V)); }

// LDS column swizzle for the GEMM tiles
__device__ __forceinline__ int swz(int c) { return c + 4 * (c >> 5); }

// ---------------------------------------------------------------------------
// XG GEMM: XG[m][n] = dot(x[m][:], W_ih[n][:]) + bias[n]   (unchanged, R6)
// ---------------------------------------------------------------------------
__global__ __launch_bounds__(256, 2) void xg_gemm(
    const float* __restrict__ xch,    // [Mc,128] chunk of x
    const float* __restrict__ W_ih,   // [256,128]
    const float* __restrict__ bias,   // [256]
    float* __restrict__ XG)           // [Mc,256]
{
    const int tid = threadIdx.x;
    const int tx  = tid & 15;
    const int ty  = tid >> 4;
    const int mt  = blockIdx.x;
    const int nt  = blockIdx.y;

    __shared__ __align__(16) float as[32][140];
    __shared__ __align__(16) float bs[32][140];

    const int n0 = nt * 128 + tx * 8;
    float4 bia = *reinterpret_cast<const float4*>(&bias[n0]);
    float4 bib = *reinterpret_cast<const float4*>(&bias[n0 + 4]);

    float acc[8][8];
#pragma unroll
    for (int r = 0; r < 8; ++r)
#pragma unroll
        for (int cc = 0; cc < 8; ++cc) acc[r][cc] = 0.0f;

    const int srow = tid >> 3;
    const int skk  = (tid & 7) * 4;

    for (int ks = 0; ks < 4; ++ks) {
        const int k0 = ks * 32;
        __syncthreads();
#pragma unroll
        for (int i = 0; i < 4; ++i) {
            const int mr = srow + 32 * i;
            float4 xa = *reinterpret_cast<const float4*>(
                &xch[(size_t)(mt * 128 + mr) * I_SZ + k0 + skk]);
            as[skk + 0][swz(mr)] = xa.x; as[skk + 1][swz(mr)] = xa.y;
            as[skk + 2][swz(mr)] = xa.z; as[skk + 3][swz(mr)] = xa.w;
            float4 wa = *reinterpret_cast<const float4*>(
                &W_ih[(size_t)(nt * 128 + mr) * I_SZ + k0 + skk]);
            bs[skk + 0][swz(mr)] = wa.x; bs[skk + 1][swz(mr)] = wa.y;
            bs[skk + 2][swz(mr)] = wa.z; bs[skk + 3][swz(mr)] = wa.w;
        }
        __syncthreads();

#pragma unroll 8
        for (int kk = 0; kk < 32; ++kk) {
            const float4 a0 = *reinterpret_cast<const float4*>(&as[kk][swz(ty * 8)]);
            const float4 a1 = *reinterpret_cast<const float4*>(&as[kk][swz(ty * 8) + 4]);
            const float4 b0 = *reinterpret_cast<const float4*>(&bs[kk][swz(tx * 8)]);
            const float4 b1 = *reinterpret_cast<const float4*>(&bs[kk][swz(tx * 8) + 4]);
            const float av[8] = {a0.x, a0.y, a0.z, a0.w, a1.x, a1.y, a1.z, a1.w};
            const float bv[8] = {b0.x, b0.y, b0.z, b0.w, b1.x, b1.y, b1.z, b1.w};
#pragma unroll
            for (int r = 0; r < 8; ++r)
#pragma unroll
                for (int cc = 0; cc < 8; ++cc)
                    acc[r][cc] = fmaf(av[r], bv[cc], acc[r][cc]);
        }
    }

#pragma unroll
    for (int r = 0; r < 8; ++r) {
        const size_t m = (size_t)(mt * 128 + ty * 8 + r);
        float4 o0 = {acc[r][0] + bia.x, acc[r][1] + bia.y,
                     acc[r][2] + bia.z, acc[r][3] + bia.w};
        float4 o1 = {acc[r][4] + bib.x, acc[r][5] + bib.y,
                     acc[r][6] + bib.z, acc[r][7] + bib.w};
        *reinterpret_cast<float4*>(&XG[m * G_SZ + n0])     = o0;
        *reinterpret_cast<float4*>(&XG[m * G_SZ + n0 + 4]) = o1;
    }
}

// ---------------------------------------------------------------------------
// Recurrence, XG LDS-staged. One block per batch element, 512 threads.
// Thread (j = tid>>1, half = tid&1) computes half of gate row j's h-dot with
// 32 register-resident W_hh floats; pair-reduced with one shfl_xor.
// XG staged in 32-step LDS sub-chunks (double buffered) so the per-step
// barrier never drains an outstanding global load.
// ---------------------------------------------------------------------------
__global__ __launch_bounds__(512, 1) void lstm_rec(
    const float* __restrict__ XG,     // [TC,B,256]
    const float* __restrict__ W_hh,   // [256,64]
    float* __restrict__ h_state,      // [B,64]
    float* __restrict__ c_state,      // [B,64]
    int TC, int first)
{
    const int b    = blockIdx.x;
    const int tid  = threadIdx.x;
    const int j    = tid >> 1;        // gate row 0..255
    const int half = tid & 1;         // h-half 0..1

    __shared__ __align__(16) float xgl[2][SUB][XROW];  // 66.6 KB
    __shared__ __align__(16) float hs[H_SZ];
    __shared__ float gs[G_SZ];

    // 32 W_hh floats -> registers (16 proven resident in R6; 2x that here)
    const float* ur = W_hh + j * H_SZ + half * 32;
    f32x8 u0, u1, u2, u3;
    LD8PIN(u0, ur) LD8PIN(u1, ur + 8) LD8PIN(u2, ur + 16) LD8PIN(u3, ur + 24)

    float c = 0.0f;
    if (tid < H_SZ) {
        hs[tid] = first ? 0.0f : h_state[b * H_SZ + tid];
        c       = first ? 0.0f : c_state[b * H_SZ + tid];
    }

    // XG staging coords: 32 rows x 16 threads x 4 float4
    const int tl = tid >> 4;          // 0..31 (t within sub-chunk)
    const int cs = tid & 15;
    {
        const float* g0 = XG + ((size_t)tl * B_SZ + b) * G_SZ + 4 * cs;
        float4 s0 = *reinterpret_cast<const float4*>(g0);
        float4 s1 = *reinterpret_cast<const float4*>(g0 + 64);
        float4 s2 = *reinterpret_cast<const float4*>(g0 + 128);
        float4 s3 = *reinterpret_cast<const float4*>(g0 + 192);
        *reinterpret_cast<float4*>(&xgl[0][tl][4 * cs])       = s0;
        *reinterpret_cast<float4*>(&xgl[0][tl][4 * cs + 64])  = s1;
        *reinterpret_cast<float4*>(&xgl[0][tl][4 * cs + 128]) = s2;
        *reinterpret_cast<float4*>(&xgl[0][tl][4 * cs + 192]) = s3;
    }
    __syncthreads();

    const int gate = j >> 6;          // wave-uniform (j spans 32 per wave)
    const int nsub = TC / SUB;

    for (int sub = 0; sub < nsub; ++sub) {
        const int  cur = sub & 1;
        const bool pf  = (sub + 1 < nsub);
        f32x4 p0, p1, p2, p3;
        if (pf) {                     // issue next sub-chunk loads early
            const float* g1 =
                XG + ((size_t)((sub + 1) * SUB + tl) * B_SZ + b) * G_SZ + 4 * cs;
            p0 = *reinterpret_cast<const f32x4*>(g1);
            p1 = *reinterpret_cast<const f32x4*>(g1 + 64);
            p2 = *reinterpret_cast<const f32x4*>(g1 + 128);
            p3 = *reinterpret_cast<const f32x4*>(g1 + 192);
        }

        for (int ts = 0; ts < SUB; ++ts) {
            const float xg = xgl[cur][ts][j];          // 2-way aliased b32
            // h-half dot: 8 wave-uniform broadcast b128 reads + 32 FMAs
            const float4* hp = reinterpret_cast<const float4*>(&hs[32 * half]);
            const float4 h0 = hp[0], h1 = hp[1], h2 = hp[2], h3 = hp[3];
            const float4 h4 = hp[4], h5 = hp[5], h6 = hp[6], h7 = hp[7];
            float a0 = 0.0f, a1 = 0.0f, a2 = 0.0f, a3 = 0.0f;
            a0 = fmaf(h0.x, u0[0], a0); a1 = fmaf(h0.y, u0[1], a1);
            a2 = fmaf(h0.z, u0[2], a2); a3 = fmaf(h0.w, u0[3], a3);
            a0 = fmaf(h1.x, u0[4], a0); a1 = fmaf(h1.y, u0[5], a1);
            a2 = fmaf(h1.z, u0[6], a2); a3 = fmaf(h1.w, u0[7], a3);
            a0 = fmaf(h2.x, u1[0], a0); a1 = fmaf(h2.y, u1[1], a1);
            a2 = fmaf(h2.z, u1[2], a2); a3 = fmaf(h2.w, u1[3], a3);
            a0 = fmaf(h3.x, u1[4], a0); a1 = fmaf(h3.y, u1[5], a1);
            a2 = fmaf(h3.z, u1[6], a2); a3 = fmaf(h3.w, u1[7], a3);
            a0 = fmaf(h4.x, u2[0], a0); a1 = fmaf(h4.y, u2[1], a1);
            a2 = fmaf(h4.z, u2[2], a2); a3 = fmaf(h4.w, u2[3], a3);
            a0 = fmaf(h5.x, u2[4], a0); a1 = fmaf(h5.y, u2[5], a1);
            a2 = fmaf(h5.z, u2[6], a2); a3 = fmaf(h5.w, u2[7], a3);
            a0 = fmaf(h6.x, u3[0], a0); a1 = fmaf(h6.y, u3[1], a1);
            a2 = fmaf(h6.z, u3[2], a2); a3 = fmaf(h6.w, u3[3], a3);
            a0 = fmaf(h7.x, u3[4], a0); a1 = fmaf(h7.y, u3[5], a1);
            a2 = fmaf(h7.z, u3[6], a2); a3 = fmaf(h7.w, u3[7], a3);

            float acc = (a0 + a1) + (a2 + a3);
            acc += __shfl_xor(acc, 1, 64);             // combine halves
            acc += xg;

            const float a = (gate == 2) ? fast_tanh(acc) : fast_sigmoid(acc);
            if (half == 0) gs[j] = a;
            __syncthreads();                           // gs ready

            if (tid < H_SZ) {                          // cell update (wave 0)
                const float ig = gs[tid];
                const float fg = gs[H_SZ + tid];
                const float gg = gs[2 * H_SZ + tid];
                const float og = gs[3 * H_SZ + tid];
                c = fg * c + ig * gg;
                hs[tid] = og * fast_tanh(c);
            }
            __syncthreads();                           // hs ready
        }

        if (pf) {                                      // park next sub-chunk
            asm volatile("" : "+v"(p0), "+v"(p1), "+v"(p2), "+v"(p3));
            *reinterpret_cast<f32x4*>(&xgl[cur ^ 1][tl][4 * cs])       = p0;
            *reinterpret_cast<f32x4*>(&xgl[cur ^ 1][tl][4 * cs + 64])  = p1;
            *reinterpret_cast<f32x4*>(&xgl[cur ^ 1][tl][4 * cs + 128]) = p2;
            *reinterpret_cast<f32x4*>(&xgl[cur ^ 1][tl][4 * cs + 192]) = p3;
        }
        __syncthreads();                               // staging visible
    }

    if (tid < H_SZ) {
        h_state[b * H_SZ + tid] = hs[tid];
        c_state[b * H_SZ + tid] = c;
    }
}

// ---------------------------------------------------------------------------
// Reverse single cell (zero init state; W_hh_r drops out) + MLP head.
// ---------------------------------------------------------------------------
__global__ __launch_bounds__(256, 1) void lstm_tail(
    const float* __restrict__ x_last,  // [B,I]
    const float* __restrict__ W_ih_r,  // [256,128]
    const float* __restrict__ b_r,     // [256]
    const float* __restrict__ h_fwd,   // [B,64]
    const float* __restrict__ fc1_w,   // [64,128]
    const float* __restrict__ fc1_b,   // [64]
    const float* __restrict__ fc2_w,   // [32,64]
    const float* __restrict__ fc2_b,   // [32]
    const float* __restrict__ fc3_w,   // [10,32]
    const float* __restrict__ fc3_b,   // [10]
    float* __restrict__ out)           // [B,10]
{
    const int b = blockIdx.x;
    const int j = threadIdx.x;

    __shared__ float xs[I_SZ];
    __shared__ float gs[G_SZ];
    __shared__ float hc[2 * H_SZ];
    __shared__ float h1[64];
    __shared__ float h2[32];

    if (j < I_SZ) xs[j] = x_last[(size_t)b * I_SZ + j];
    if (j < H_SZ) hc[j] = h_fwd[b * H_SZ + j];
    __syncthreads();

    float a0 = b_r[j], a1 = 0.0f, a2 = 0.0f, a3 = 0.0f;
    const float* wrow = W_ih_r + j * I_SZ;
#pragma unroll
    for (int kk = 0; kk < I_SZ; kk += 4) {
        float4 wv = *reinterpret_cast<const float4*>(wrow + kk);
        a0 = fmaf(xs[kk + 0], wv.x, a0);
        a1 = fmaf(xs[kk + 1], wv.y, a1);
        a2 = fmaf(xs[kk + 2], wv.z, a2);
        a3 = fmaf(xs[kk + 3], wv.w, a3);
    }
    const float acc = (a0 + a1) + (a2 + a3);
    const int gate = j >> 6;
    gs[j] = (gate == 2) ? tanhf(acc) : 1.0f / (1.0f + expf(-acc));
    __syncthreads();

    if (j < H_SZ) {
        const float cc = gs[j] * gs[2 * H_SZ + j];     // i*g (c0 = 0)
        hc[H_SZ + j] = gs[3 * H_SZ + j] * tanhf(cc);
    }
    __syncthreads();

    if (j < 64) {
        float s0 = fc1_b[j], s1 = 0.0f, s2 = 0.0f, s3 = 0.0f;
        const float* w = fc1_w + j * 128;
#pragma unroll
        for (int kk = 0; kk < 128; kk += 4) {
            float4 wv = *reinterpret_cast<const float4*>(w + kk);
            s0 = fmaf(hc[kk + 0], wv.x, s0);
            s1 = fmaf(hc[kk + 1], wv.y, s1);
            s2 = fmaf(hc[kk + 2], wv.z, s2);
            s3 = fmaf(hc[kk + 3], wv.w, s3);
        }
        h1[j] = fmaxf((s0 + s1) + (s2 + s3), 0.0f);
    }
    __syncthreads();

    if (j < 32) {
        float s0 = fc2_b[j], s1 = 0.0f, s2 = 0.0f, s3 = 0.0f;
        const float* w = fc2_w + j * 64;
#pragma unroll
        for (int kk = 0; kk < 64; kk += 4) {
            float4 wv = *reinterpret_cast<const float4*>(w + kk);
            s0 = fmaf(h1[kk + 0], wv.x, s0);
            s1 = fmaf(h1[kk + 1], wv.y, s1);
            s2 = fmaf(h1[kk + 2], wv.z, s2);
            s3 = fmaf(h1[kk + 3], wv.w, s3);
        }
        h2[j] = fmaxf((s0 + s1) + (s2 + s3), 0.0f);
    }
    __syncthreads();

    if (j < 10) {
        float s = fc3_b[j];
#pragma unroll
        for (int kk = 0; kk < 32; ++kk) s = fmaf(h2[kk], fc3_w[j * 32 + kk], s);
        out[b * 10 + j] = s;
    }
}

extern "C" void kernel_launch(void* const* d_in, const int* in_sizes, int n_in,
                              void* d_out, int out_size, void* d_ws, size_t ws_size,
                              hipStream_t stream) {
    const float* x      = (const float*)d_in[0];
    const float* W_ih_f = (const float*)d_in[1];
    const float* W_hh_f = (const float*)d_in[2];
    const float* b_f    = (const float*)d_in[3];
    const float* W_ih_r = (const float*)d_in[4];
    // d_in[5] = W_hh_r : unused (zero initial state in reverse single step)
    const float* b_r    = (const float*)d_in[6];
    const float* fc1_w  = (const float*)d_in[7];
    const float* fc1_b  = (const float*)d_in[8];
    const float* fc2_w  = (const float*)d_in[9];
    const float* fc2_b  = (const float*)d_in[10];
    const float* fc3_w  = (const float*)d_in[11];
    const float* fc3_b  = (const float*)d_in[12];
    float* out = (float*)d_out;

    // time-chunk size: largest TC whose XG buffer (+state) fits in ws
    int TC = 1024;
    while (TC > 64 &&
           (size_t)TC * B_SZ * G_SZ * 4 + 2 * B_SZ * H_SZ * 4 > ws_size)
        TC >>= 1;

    float* XG      = (float*)d_ws;
    float* h_state = (float*)((char*)d_ws + (size_t)TC * B_SZ * G_SZ * 4);
    float* c_state = h_state + B_SZ * H_SZ;

    const int NCH = T_LEN / TC;
    for (int ch = 0; ch < NCH; ++ch) {
        const float* xch = x + (size_t)ch * TC * B_SZ * I_SZ;
        hipLaunchKernelGGL(xg_gemm, dim3(TC * B_SZ / 128, 2), dim3(256), 0,
                           stream, xch, W_ih_f, b_f, XG);
        hipLaunchKernelGGL(lstm_rec, dim3(B_SZ), dim3(512), 0, stream,
                           XG, W_hh_f, h_state, c_state, TC, ch == 0 ? 1 : 0);
    }

    const float* x_last = x + (size_t)(T_LEN - 1) * B_SZ * I_SZ;
    hipLaunchKernelGGL(lstm_tail, dim3(B_SZ), dim3(256), 0, stream,
                       x_last, W_ih_r, b_r, h_state,
                       fc1_w, fc1_b, fc2_w, fc2_b, fc3_w, fc3_b, out);
}